// Round 1
// baseline (409.198 us; speedup 1.0000x reference)
//
#include <hip/hip_runtime.h>
#include <hip/hip_bf16.h>

typedef __attribute__((ext_vector_type(8))) short short8;
typedef __attribute__((ext_vector_type(4))) float floatx4;
typedef __attribute__((ext_vector_type(2))) float floatx2;

#define LDK 136   // padded LDS row length in bf16 elements (17 chunks of 16B)

__device__ __forceinline__ unsigned short f2bf(float x) {
    unsigned u = __builtin_bit_cast(unsigned, x);
    return (unsigned short)((u + 0x7fffu + ((u >> 16) & 1u)) >> 16);
}

// One kernel used for both passes.
// Pass1 (ACCUM=false): block = (b, r). s0 = 128*256, s1 = 256.
//   out[b,r,c,d] = sum_k softmax_k(atten_x[b,r,c,k] + g(c,k)) * value[b,r,k,d]
// Pass2 (ACCUM=true):  block = (b, c). s0 = 256, s1 = 128*256.
//   out[b,r,c,d] += sum_k softmax_k(atten_y[b,c,r,k] + g(r,k)) * value[b,k,c,d]
// In both: A-rows are contiguous 128-float rows at abase + row*128,
// V k-rows at vbase + k*s1, out n-rows at obase + n*s1.
template <bool ACCUM>
__global__ __launch_bounds__(512) void gtrans(
    const float* __restrict__ atten, const float* __restrict__ value,
    float* __restrict__ out, const float* __restrict__ shiftp,
    const float* __restrict__ biasp, int s0, int s1)
{
    __shared__ short Buf[128 * LDK];   // 34816 B, reused: As -> V^T halves

    const int bi   = blockIdx.x;
    const int b    = bi >> 7;
    const int i    = bi & 127;
    const int tid  = threadIdx.x;
    const int lane = tid & 63;
    const int w    = tid >> 6;   // wave 0..7

    const float shift = shiftp[0];
    const float bias  = biasp[0];

    const float* abase = atten + (size_t)bi * (128 * 128);
    const float* vbase = value + (size_t)b * (128 * 128 * 256) + (size_t)i * s0;
    float*       obase = out   + (size_t)b * (128 * 128 * 256) + (size_t)i * s0;

    // ---- Phase 1: rowwise softmax(A + g) -> Buf (bf16). Wave w owns rows 16w..16w+15.
    {
        floatx2 v[16];
#pragma unroll
        for (int j = 0; j < 16; ++j) {
            int c = w * 16 + j;
            v[j] = *(const floatx2*)(abase + c * 128 + 2 * lane);
        }
#pragma unroll
        for (int j = 0; j < 16; ++j) {
            int c = w * 16 + j;
            float d0 = (float)(2 * lane)     - (float)c;
            float d1 = (float)(2 * lane + 1) - (float)c;
            float a0 = v[j].x - (shift * d0 * d0 + bias);
            float a1 = v[j].y - (shift * d1 * d1 + bias);
            float m = fmaxf(a0, a1);
#pragma unroll
            for (int s = 1; s < 64; s <<= 1) m = fmaxf(m, __shfl_xor(m, s, 64));
            float e0 = __expf(a0 - m);
            float e1 = __expf(a1 - m);
            float ssum = e0 + e1;
#pragma unroll
            for (int s = 1; s < 64; s <<= 1) ssum += __shfl_xor(ssum, s, 64);
            float r = 1.0f / ssum;
            unsigned p = (unsigned)f2bf(e0 * r) | ((unsigned)f2bf(e1 * r) << 16);
            *(unsigned*)(&Buf[c * LDK + 2 * lane]) = p;
        }
    }
    __syncthreads();

    // ---- Phase 2: this wave's 16 softmax rows -> B-operand fragments in registers.
    // B[k][n]: n = lane&15 (row 16w+n of P), k = (lane>>4)*8 + j, per 32-k step.
    short8 bfrag[4];
    {
        int n  = w * 16 + (lane & 15);
        int kq = (lane >> 4) * 8;
#pragma unroll
        for (int ks = 0; ks < 4; ++ks)
            bfrag[ks] = *(const short8*)(&Buf[n * LDK + ks * 32 + kq]);
    }
    __syncthreads();

    // ---- Phase 3: two 128-wide d-halves. Buf now holds V^T (d-local rows, k cols).
    floatx4 acc[8];
    const int am = lane & 15;
    const int kq = (lane >> 4) * 8;
#pragma unroll
    for (int half = 0; half < 2; ++half) {
        {   // stage V^T: wave w loads k-rows 16w..16w+15, 128 d (this half) each
            floatx2 vv[16];
#pragma unroll
            for (int j = 0; j < 16; ++j) {
                int k = w * 16 + j;
                vv[j] = *(const floatx2*)(vbase + (size_t)k * s1 + half * 128 + 2 * lane);
            }
#pragma unroll
            for (int j = 0; j < 16; ++j) {
                int k  = w * 16 + j;
                int dl = 2 * lane;
                Buf[dl * LDK + k]       = (short)f2bf(vv[j].x);
                Buf[(dl + 1) * LDK + k] = (short)f2bf(vv[j].y);
            }
        }
        __syncthreads();

#pragma unroll
        for (int t = 0; t < 8; ++t) acc[t] = (floatx4)0.0f;

        // D[m=d][n=c]: A-operand from V^T rows (m = d), B-operand = bfrag (n = P row)
#pragma unroll
        for (int ks = 0; ks < 4; ++ks) {
#pragma unroll
            for (int t = 0; t < 8; ++t) {
                short8 af = *(const short8*)(&Buf[(t * 16 + am) * LDK + ks * 32 + kq]);
                acc[t] = __builtin_amdgcn_mfma_f32_16x16x32_bf16(af, bfrag[ks], acc[t], 0, 0, 0);
            }
        }

        // epilogue: lane holds col n = lane&15 (out row), 4 consecutive d per acc reg
        {
            int n = w * 16 + (lane & 15);
            float* orow = obase + (size_t)n * s1 + half * 128 + (lane >> 4) * 4;
#pragma unroll
            for (int t = 0; t < 8; ++t) {
                float* p = orow + t * 16;
                floatx4 res = acc[t];
                if (ACCUM) {
                    floatx4 old = *(const floatx4*)p;
                    res = res + old;
                }
                *(floatx4*)p = res;
            }
        }
        __syncthreads();   // before V^T restage / kernel end
    }
}

extern "C" void kernel_launch(void* const* d_in, const int* in_sizes, int n_in,
                              void* d_out, int out_size, void* d_ws, size_t ws_size,
                              hipStream_t stream) {
    const float* atten_x = (const float*)d_in[1];
    const float* atten_y = (const float*)d_in[2];
    const float* value   = (const float*)d_in[3];
    const float* shiftp  = (const float*)d_in[4];
    const float* biasp   = (const float*)d_in[5];
    float* out = (float*)d_out;

    dim3 grid(1024), block(512);
    // Pass 1: out = einsum('brck,brkd->brcd', softmax(Ax+gx), value)
    gtrans<false><<<grid, block, 0, stream>>>(atten_x, value, out, shiftp, biasp,
                                              128 * 256, 256);
    // Pass 2: out += einsum('bcrk,bkcd->brcd', softmax(Ay+gy), value)
    gtrans<true><<<grid, block, 0, stream>>>(atten_y, value, out, shiftp, biasp,
                                             256, 128 * 256);
}